// Round 2
// baseline (169.430 us; speedup 1.0000x reference)
//
#include <hip/hip_runtime.h>
#include <math.h>

// Problem constants (match reference)
#define BB 16384
#define TT 99
#define EE 10
#define RR 10
#define LL 3
#define TILE 33          // 99 = 3 * 33
#define SROW 334         // states LDS row stride in floats; 334*4/8 = 167 (odd) -> conflict-free b64
#define PROW 101         // probs LDS row stride in floats (odd)
#define YROW 36          // label-class byte stride

// tanh(x) = 1 - 2/(exp(2x)+1); exact limits at +-inf.
__device__ __forceinline__ float fast_tanh(float x) {
    float e = __expf(2.0f * x);
    return fmaf(-2.0f, __builtin_amdgcn_rcpf(e + 1.0f), 1.0f);
}

// One thread per batch row; block = 1 wave (64 lanes) -> no __syncthreads needed
// (per-wave DS ops are in-order; cross-lane LDS visibility after lgkmcnt).
__global__ __launch_bounds__(64, 1)
void rnn_fused_kernel(const int* __restrict__ tok_ids,
                      const float* __restrict__ labels,
                      const float* __restrict__ emb,
                      const float* __restrict__ W,
                      const float* __restrict__ U,
                      const float* __restrict__ bvec,
                      const float* __restrict__ Wo,
                      const float* __restrict__ bo,
                      float* __restrict__ states_out,
                      float* __restrict__ probs_out,
                      float* __restrict__ ws)
{
    __shared__ float          s_states[64 * SROW];  // 85.5 KB
    __shared__ float          s_probs [64 * PROW];  // 25.9 KB
    __shared__ int            s_tok   [64 * TILE];  //  8.4 KB
    __shared__ unsigned char  s_y     [64 * YROW];  //  2.3 KB

    const int l    = threadIdx.x;
    const int row0 = blockIdx.x * 64;

    // ---- uniform small weights (compiler puts these in SGPRs) ----
    float Ur[RR][RR];
#pragma unroll
    for (int i = 0; i < RR; ++i)
#pragma unroll
        for (int j = 0; j < RR; ++j)
            Ur[i][j] = U[i * RR + j];

    // c[tok][j] = b[j] + emb[tok] . W[:,j]  (token 0 is masked -> never used)
    float c1[RR], c2[RR];
#pragma unroll
    for (int j = 0; j < RR; ++j) { c1[j] = bvec[j]; c2[j] = bvec[j]; }
#pragma unroll
    for (int i = 0; i < EE; ++i) {
        float e1 = emb[1 * EE + i];
        float e2 = emb[2 * EE + i];
#pragma unroll
        for (int j = 0; j < RR; ++j) {
            float w = W[i * RR + j];
            c1[j] = fmaf(e1, w, c1[j]);
            c2[j] = fmaf(e2, w, c2[j]);
        }
    }

    float Wor[RR][LL];
#pragma unroll
    for (int j = 0; j < RR; ++j)
#pragma unroll
        for (int lc = 0; lc < LL; ++lc)
            Wor[j][lc] = Wo[j * LL + lc];
    const float bo0 = bo[0], bo1 = bo[1], bo2 = bo[2];

    float h[RR];
#pragma unroll
    for (int j = 0; j < RR; ++j) h[j] = 0.0f;

    float loss_acc = 0.0f;
    int corr = 0;

    const size_t grow0 = (size_t)row0 * TT;   // global row base (in time steps)

#pragma unroll 1
    for (int k = 0; k < 3; ++k) {
        const int t0 = k * TILE;

        // ---- preamble: coalesced token load -> LDS ----
#pragma unroll 4
        for (int i = 0; i < TILE; ++i) {
            const int q  = l + 64 * i;           // piece id, 64*33 pieces
            const int r  = q / TILE;
            const int tt = q - r * TILE;
            s_tok[r * TILE + tt] = tok_ids[(grow0 + (size_t)r * TT) + t0 + tt];
        }
        // ---- preamble: coalesced label load -> class byte in LDS ----
#pragma unroll 4
        for (int i = 0; i < TILE; ++i) {
            const int q  = l + 64 * i;
            const int r  = q / TILE;
            const int tt = q - r * TILE;
            const float* lp = labels + ((grow0 + (size_t)r * TT) + t0 + tt) * LL;
            const float la1 = lp[1], la2 = lp[2];
            s_y[r * YROW + tt] = (la1 > 0.5f) ? (unsigned char)1
                               : ((la2 > 0.5f) ? (unsigned char)2 : (unsigned char)0);
        }

        // ---- compute: 33 steps, registers + LDS only (no global memory) ----
#pragma unroll 1
        for (int t = 0; t < TILE; ++t) {
            const int  tk   = s_tok[l * TILE + t];
            const bool is1  = (tk == 1);
            const bool live = (tk != 0);

            float a[RR];
#pragma unroll
            for (int j = 0; j < RR; ++j) a[j] = is1 ? c1[j] : c2[j];
#pragma unroll
            for (int i = 0; i < RR; ++i) {
                const float hi = h[i];
#pragma unroll
                for (int j = 0; j < RR; ++j)
                    a[j] = fmaf(hi, Ur[i][j], a[j]);
            }
#pragma unroll
            for (int j = 0; j < RR; ++j) {
                const float hn = fast_tanh(a[j]);
                h[j] = live ? hn : h[j];         // Keras masking: carry h
            }

            // states -> LDS (5x ds_write_b64, conflict-free stride)
            float* sp = s_states + l * SROW + t * RR;
#pragma unroll
            for (int j = 0; j < RR; j += 2)
                *reinterpret_cast<float2*>(sp + j) = make_float2(h[j], h[j + 1]);

            // dense (10x3) + softmax(3)
            float l0 = bo0, l1 = bo1, l2 = bo2;
#pragma unroll
            for (int j = 0; j < RR; ++j) {
                l0 = fmaf(h[j], Wor[j][0], l0);
                l1 = fmaf(h[j], Wor[j][1], l1);
                l2 = fmaf(h[j], Wor[j][2], l2);
            }
            const float m  = fmaxf(l0, fmaxf(l1, l2));
            const float e0 = __expf(l0 - m), e1 = __expf(l1 - m), e2 = __expf(l2 - m);
            const float rs = __builtin_amdgcn_rcpf(e0 + e1 + e2);
            const float p0 = e0 * rs, p1 = e1 * rs, p2 = e2 * rs;

            float* pp = s_probs + l * PROW + t * LL;
            pp[0] = p0; pp[1] = p1; pp[2] = p2;

            // loss (labels are exact one-hot -> single log) + accuracy
            const int   y  = (int)s_y[l * YROW + t];
            const float py = (y == 0) ? p0 : ((y == 1) ? p1 : p2);
            const float pc = fminf(fmaxf(py, 1e-7f), 1.0f);
            loss_acc -= __logf(pc);

            int ap = 0; float pm = p0;
            if (p1 > pm) { ap = 1; pm = p1; }
            if (p2 > pm) { ap = 2; }
            corr += (ap == y) ? 1 : 0;
        }

        // ---- flush states: LDS -> global, lane-cooperative (coalesced) ----
        // per row: 330 floats = 165 float2 pieces; 64 rows -> 165 pieces/lane
        const size_t sbase = (grow0 + t0) * RR;
#pragma unroll 4
        for (int i = 0; i < 165; ++i) {
            const int q   = l + 64 * i;
            const int r   = q / 165;
            const int off = q - r * 165;
            const float2 v = *reinterpret_cast<const float2*>(&s_states[r * SROW + off * 2]);
            *reinterpret_cast<float2*>(&states_out[sbase + (size_t)r * (TT * RR) + off * 2]) = v;
        }
        // ---- flush probs: per row 99 floats; 99 pieces/lane ----
        const size_t pbase = (grow0 + t0) * LL;
#pragma unroll 4
        for (int i = 0; i < 99; ++i) {
            const int q   = l + 64 * i;
            const int r   = q / 99;
            const int off = q - r * 99;
            probs_out[pbase + (size_t)r * (TT * LL) + off] = s_probs[r * PROW + off];
        }
    }

    // ---- wave(=block) reduction -> one partial per block (deterministic) ----
    float ls = loss_acc;
    float cs = (float)corr;
#pragma unroll
    for (int off = 32; off > 0; off >>= 1) {
        ls += __shfl_down(ls, off, 64);
        cs += __shfl_down(cs, off, 64);
    }
    if (l == 0) {
        ws[blockIdx.x]       = ls;
        ws[256 + blockIdx.x] = cs;
    }
}

__global__ __launch_bounds__(256)
void finalize_kernel(const float* __restrict__ ws, float* __restrict__ out_tail)
{
    __shared__ float sl[4], sc[4];
    const int t = threadIdx.x;
    float ls = ws[t];
    float cs = ws[256 + t];
#pragma unroll
    for (int off = 32; off > 0; off >>= 1) {
        ls += __shfl_down(ls, off, 64);
        cs += __shfl_down(cs, off, 64);
    }
    if ((t & 63) == 0) { sl[t >> 6] = ls; sc[t >> 6] = cs; }
    __syncthreads();
    if (t == 0) {
        const float L = sl[0] + sl[1] + sl[2] + sl[3];
        const float C = sc[0] + sc[1] + sc[2] + sc[3];
        const float inv = 1.0f / (float)((size_t)BB * TT);
        out_tail[0] = C * inv;   // accuracy
        out_tail[1] = L * inv;   // loss
    }
}

extern "C" void kernel_launch(void* const* d_in, const int* in_sizes, int n_in,
                              void* d_out, int out_size, void* d_ws, size_t ws_size,
                              hipStream_t stream)
{
    const int*   tok    = (const int*)  d_in[0];
    const float* labels = (const float*)d_in[1];
    // d_in[2] = mask (unused by reference math)
    const float* emb = (const float*)d_in[3];
    const float* W   = (const float*)d_in[4];
    const float* U   = (const float*)d_in[5];
    const float* bv  = (const float*)d_in[6];
    const float* Wo  = (const float*)d_in[7];
    const float* bo  = (const float*)d_in[8];

    float* out    = (float*)d_out;
    float* states = out;                                  // [B,T,10]
    float* probs  = out + (size_t)BB * TT * RR;           // [B,T,3]
    float* tail   = out + (size_t)BB * TT * (RR + LL);    // accuracy, loss
    float* ws     = (float*)d_ws;                         // 512 floats used

    rnn_fused_kernel<<<BB / 64, 64, 0, stream>>>(tok, labels, emb, W, U, bv, Wo, bo,
                                                 states, probs, ws);
    finalize_kernel<<<1, 256, 0, stream>>>(ws, tail);
}

// Round 3
// 65.196 us; speedup vs baseline: 2.5988x; 2.5988x over previous
//
#include <hip/hip_runtime.h>
#include <math.h>

// Problem constants
#define BB 16384
#define TT 99
#define RR 10
#define LL 3
#define TILE 33          // 99 = 3*33
#define RPW 8            // rows per wave (8 lanes per row)
#define WPB 4            // waves per block (block = 256 threads, 32 rows)
#define STRIDE_T 12      // padded floats per step in state stage (48B -> float4-aligned)
#define ST_W (RPW*TILE*STRIDE_T)   // 3168 floats per wave
#define PR_W (RPW*TILE*LL)         // 792 floats per wave
#define TKROW 100                  // byte stride per row in token/label stage

// tanh(x) = 1 - 2/(exp(2x)+1); exact limits at +-inf.
__device__ __forceinline__ float fast_tanh(float x) {
    float e = __expf(2.0f * x);
    return fmaf(-2.0f, __builtin_amdgcn_rcpf(e + 1.0f), 1.0f);
}

// 8 lanes per row; lane l: r = l>>3 (row in wave), g = l&7 (slot).
// Slot g owns hidden unit g; slots 0,1 additionally own units 8,9.
// Full h is rebuilt per step via the LDS state-staging tile (write own, read 10).
__global__ __launch_bounds__(256, 2)
void rnn_split_kernel(const int* __restrict__ tok_ids,
                      const float* __restrict__ labels,
                      const float* __restrict__ emb,
                      const float* __restrict__ W,
                      const float* __restrict__ U,
                      const float* __restrict__ bvec,
                      const float* __restrict__ Wo,
                      const float* __restrict__ bo,
                      float* __restrict__ states_out,
                      float* __restrict__ probs_out,
                      float* __restrict__ ws)
{
    __shared__ float         s_st[WPB][ST_W];   // 50688 B: state stage [r][tt][12]
    __shared__ float         s_pr[WPB][PR_W];   // 12672 B: probs stage [r][tt][3]
    __shared__ unsigned char s_tk[WPB][RPW*TKROW]; // 3200 B
    __shared__ unsigned char s_yb[WPB][RPW*TKROW]; // 3200 B   (total 69760 B)

    const int tid = threadIdx.x;
    const int w   = tid >> 6;
    const int l   = tid & 63;
    const int r   = l >> 3;
    const int g   = l & 7;
    const int rb  = l & ~7;                       // base lane of this row-group
    const int rowbase = blockIdx.x * (WPB * RPW) + w * RPW;

    // ---- stage tokens + label classes for the whole sequence (coalesced-ish) ----
    for (int i = 0; i < 13; ++i) {
        const int q = l + 64 * i;
        if (q < RPW * TT) {
            const int rr = q / TT;
            const int t  = q - rr * TT;
            const int gi = (rowbase + rr) * TT + t;
            s_tk[w][rr * TKROW + t] = (unsigned char)tok_ids[gi];
            const float* lp = labels + (size_t)gi * LL;
            const float la1 = lp[1], la2 = lp[2];
            s_yb[w][rr * TKROW + t] =
                (la1 > 0.5f) ? (unsigned char)1 : ((la2 > 0.5f) ? (unsigned char)2
                                                                : (unsigned char)0);
        }
    }

    // ---- per-lane weight columns ----
    const int jg0 = g;
    const int jg1 = (g < 2) ? 8 + g : g;          // duplicate for g>=2 (results unused)
    float U0[RR], U1[RR], Woc[RR];
    float c1_0 = bvec[jg0], c2_0 = c1_0;
    float c1_1 = bvec[jg1], c2_1 = c1_1;
#pragma unroll
    for (int i = 0; i < RR; ++i) {
        U0[i] = U[i * RR + jg0];
        U1[i] = U[i * RR + jg1];
        const float w0 = W[i * RR + jg0];
        const float w1 = W[i * RR + jg1];
        c1_0 = fmaf(emb[RR + i],     w0, c1_0);   // token 1 row of emb
        c2_0 = fmaf(emb[2 * RR + i], w0, c2_0);   // token 2 row
        c1_1 = fmaf(emb[RR + i],     w1, c1_1);
        c2_1 = fmaf(emb[2 * RR + i], w1, c2_1);
    }
    const int gc = (g < 3) ? g : 2;               // logit column this lane computes
#pragma unroll
    for (int i = 0; i < RR; ++i) Woc[i] = Wo[i * LL + gc];
    const float boc = bo[gc];

    float hf[RR];
#pragma unroll
    for (int i = 0; i < RR; ++i) hf[i] = 0.0f;
    float ho0 = 0.0f, ho1 = 0.0f;                 // this lane's owned h units
    float loss_acc = 0.0f;
    int   corr = 0;

#pragma unroll 1
    for (int k = 0; k < 3; ++k) {
#pragma unroll 1
        for (int tt = 0; tt < TILE; ++tt) {
            const int t  = k * TILE + tt;
            const int tk = (int)s_tk[w][r * TKROW + t];
            const int yv = (int)s_yb[w][r * TKROW + t];

            float a0 = (tk == 1) ? c1_0 : c2_0;
            float a1 = (tk == 1) ? c1_1 : c2_1;
#pragma unroll
            for (int i = 0; i < RR; ++i) {
                a0 = fmaf(hf[i], U0[i], a0);
                a1 = fmaf(hf[i], U1[i], a1);
            }
            const float hn0 = fast_tanh(a0);
            const float hn1 = fast_tanh(a1);
            if (tk != 0) { ho0 = hn0; ho1 = hn1; }    // Keras masking (cndmask)

            // stage own units; rebuild full h from the staging tile
            float* sp = &s_st[w][(r * TILE + tt) * STRIDE_T];
            sp[g] = ho0;
            if (g < 2) sp[8 + g] = ho1;
            const float4 A  = *reinterpret_cast<const float4*>(sp);
            const float4 Bv = *reinterpret_cast<const float4*>(sp + 4);
            const float2 Cv = *reinterpret_cast<const float2*>(sp + 8);
            hf[0] = A.x;  hf[1] = A.y;  hf[2] = A.z;  hf[3] = A.w;
            hf[4] = Bv.x; hf[5] = Bv.y; hf[6] = Bv.z; hf[7] = Bv.w;
            hf[8] = Cv.x; hf[9] = Cv.y;

            // dense: one logit per lane (lanes >=3 redundantly compute logit 2)
            float lg = boc;
#pragma unroll
            for (int i = 0; i < RR; ++i) lg = fmaf(hf[i], Woc[i], lg);
            const float l0 = __shfl(lg, rb + 0, 64);
            const float l1 = __shfl(lg, rb + 1, 64);
            const float l2 = __shfl(lg, rb + 2, 64);

            const float m  = fmaxf(l0, fmaxf(l1, l2));
            const float e0 = __expf(l0 - m), e1 = __expf(l1 - m), e2 = __expf(l2 - m);
            const float rs = __builtin_amdgcn_rcpf(e0 + e1 + e2);
            const float p0 = e0 * rs, p1 = e1 * rs, p2 = e2 * rs;

            if (g < 3)
                s_pr[w][(r * TILE + tt) * LL + g] = (g == 0) ? p0 : ((g == 1) ? p1 : p2);

            const float py = (yv == 0) ? p0 : ((yv == 1) ? p1 : p2);
            loss_acc -= __logf(fminf(fmaxf(py, 1e-7f), 1.0f));

            int ap = 0; float pm = p0;
            if (p1 > pm) { ap = 1; pm = p1; }
            if (p2 > pm) { ap = 2; }
            corr += (ap == yv) ? 1 : 0;
        }

        // ---- flush states: LDS -> global, coalesced float2 pieces ----
        // per wave: 8 rows x 33 steps x 10 = 2640 floats = 1320 float2 pieces
        {
            const size_t sbase = (size_t)rowbase * (TT * RR) + (size_t)k * TILE * RR;
            for (int i = 0; i < 21; ++i) {
                const int p2 = l + 64 * i;
                if (p2 < RPW * TILE * RR / 2) {
                    const int rr = p2 / 165;
                    const int m  = 2 * (p2 - rr * 165);   // even, < 330
                    const int tl = m / RR;
                    const int j  = m - tl * RR;           // even, <= 8
                    const float2 v = *reinterpret_cast<const float2*>(
                        &s_st[w][(rr * TILE + tl) * STRIDE_T + j]);
                    *reinterpret_cast<float2*>(
                        &states_out[sbase + (size_t)rr * (TT * RR) + tl * RR + j]) = v;
                }
            }
        }
        // ---- flush probs: 792 floats, coalesced dwords ----
        {
            const size_t pbase = (size_t)rowbase * (TT * LL) + (size_t)k * TILE * LL;
            for (int i = 0; i < 13; ++i) {
                const int p = l + 64 * i;
                if (p < PR_W) {
                    const int rr = p / 99;
                    const int m  = p - rr * 99;
                    probs_out[pbase + (size_t)rr * (TT * LL) + m] = s_pr[w][rr * 99 + m];
                }
            }
        }
        // next tile reuses s_st/s_pr: per-wave DS ordering guarantees safety (no barriers)
    }

    // ---- reduce loss/corr: valid only on g==0 lanes (one per row) ----
    float lsv = (g == 0) ? loss_acc : 0.0f;
    float csv = (g == 0) ? (float)corr : 0.0f;
#pragma unroll
    for (int off = 32; off > 0; off >>= 1) {
        lsv += __shfl_down(lsv, off, 64);
        csv += __shfl_down(csv, off, 64);
    }
    if (l == 0) {
        const int wg = blockIdx.x * WPB + w;      // 0..2047
        ws[wg]        = lsv;
        ws[2048 + wg] = csv;
    }
}

__global__ __launch_bounds__(256)
void finalize_kernel(const float* __restrict__ ws, float* __restrict__ out_tail)
{
    __shared__ float sl[4], sc[4];
    const int t = threadIdx.x;
    float ls = 0.0f, cs = 0.0f;
#pragma unroll
    for (int i = 0; i < 8; ++i) {
        ls += ws[t + 256 * i];
        cs += ws[2048 + t + 256 * i];
    }
#pragma unroll
    for (int off = 32; off > 0; off >>= 1) {
        ls += __shfl_down(ls, off, 64);
        cs += __shfl_down(cs, off, 64);
    }
    if ((t & 63) == 0) { sl[t >> 6] = ls; sc[t >> 6] = cs; }
    __syncthreads();
    if (t == 0) {
        const float L = sl[0] + sl[1] + sl[2] + sl[3];
        const float C = sc[0] + sc[1] + sc[2] + sc[3];
        const float inv = 1.0f / (float)((size_t)BB * TT);
        out_tail[0] = C * inv;   // accuracy
        out_tail[1] = L * inv;   // loss
    }
}

extern "C" void kernel_launch(void* const* d_in, const int* in_sizes, int n_in,
                              void* d_out, int out_size, void* d_ws, size_t ws_size,
                              hipStream_t stream)
{
    const int*   tok    = (const int*)  d_in[0];
    const float* labels = (const float*)d_in[1];
    // d_in[2] = mask (unused by reference math)
    const float* emb = (const float*)d_in[3];
    const float* W   = (const float*)d_in[4];
    const float* U   = (const float*)d_in[5];
    const float* bv  = (const float*)d_in[6];
    const float* Wo  = (const float*)d_in[7];
    const float* bo  = (const float*)d_in[8];

    float* out    = (float*)d_out;
    float* states = out;                                  // [B,T,10]
    float* probs  = out + (size_t)BB * TT * RR;           // [B,T,3]
    float* tail   = out + (size_t)BB * TT * (RR + LL);    // accuracy, loss
    float* ws     = (float*)d_ws;                         // 4096 floats used

    rnn_split_kernel<<<BB / (WPB * RPW), 256, 0, stream>>>(
        tok, labels, emb, W, U, bv, Wo, bo, states, probs, ws);
    finalize_kernel<<<1, 256, 0, stream>>>(ws, tail);
}